// Round 8
// baseline (221.203 us; speedup 1.0000x reference)
//
#include <hip/hip_runtime.h>

typedef unsigned short u16;
typedef unsigned int u32;
typedef __attribute__((ext_vector_type(8))) short short8;  // 8 bf16 (4 VGPRs)
typedef __attribute__((ext_vector_type(4))) float f32x4;   // MFMA acc

// ---- bf16 helpers ----
__device__ __forceinline__ float bf2f(u16 v) {
  return __uint_as_float(((u32)v) << 16);
}
__device__ __forceinline__ u16 f2bf(float f) {
  u32 u = __float_as_uint(f);
  return (u16)((u + 0x7fffu + ((u >> 16) & 1u)) >> 16);  // RNE
}
__device__ __forceinline__ u32 pk2(float lo, float hi) {
  return (u32)f2bf(lo) | ((u32)f2bf(hi) << 16);
}

// flagged input loads (fp32 vs bf16 decided at runtime, wave-uniform branch)
__device__ __forceinline__ float ld1in(const void* p, size_t i, bool f32) {
  return f32 ? ((const float*)p)[i] : bf2f(((const u16*)p)[i]);
}
__device__ __forceinline__ float4 ld4in(const void* p, size_t i, bool f32) {
  if (f32) return *(const float4*)((const float*)p + i);
  ushort4 u = *(const ushort4*)((const u16*)p + i);
  return make_float4(bf2f(u.x), bf2f(u.y), bf2f(u.z), bf2f(u.w));
}
__device__ __forceinline__ void ld8in(const void* p, size_t i, bool f32, float* v) {
  if (f32) {
    float4 a = *(const float4*)((const float*)p + i);
    float4 b = *(const float4*)((const float*)p + i + 4);
    v[0] = a.x; v[1] = a.y; v[2] = a.z; v[3] = a.w;
    v[4] = b.x; v[5] = b.y; v[6] = b.z; v[7] = b.w;
  } else {
    ushort4 a = *(const ushort4*)((const u16*)p + i);
    ushort4 b = *(const ushort4*)((const u16*)p + i + 4);
    v[0] = bf2f(a.x); v[1] = bf2f(a.y); v[2] = bf2f(a.z); v[3] = bf2f(a.w);
    v[4] = bf2f(b.x); v[5] = bf2f(b.y); v[6] = bf2f(b.z); v[7] = bf2f(b.w);
  }
}

// ws element store (dtype = template param) + loads
__device__ __forceinline__ void st1ws(float* p, size_t i, float v) { p[i] = v; }
__device__ __forceinline__ void st1ws(u16* p, size_t i, float v) { p[i] = f2bf(v); }
__device__ __forceinline__ float4 ld4ws(const float* p, size_t i) { return *(const float4*)(p + i); }
__device__ __forceinline__ float4 ld4ws(const u16* p, size_t i) {
  ushort4 u = *(const ushort4*)(p + i);
  return make_float4(bf2f(u.x), bf2f(u.y), bf2f(u.z), bf2f(u.w));
}
// 8 consecutive ws elems -> uint4 of bf16 pairs (identity copy on bf16 ws)
template <typename WT>
__device__ __forceinline__ uint4 ld8ws_pk(const WT* p, size_t i) {
  float4 a = ld4ws(p, i), b = ld4ws(p, i + 4);
  uint4 r;
  r.x = pk2(a.x, a.y); r.y = pk2(a.z, a.w);
  r.z = pk2(b.x, b.y); r.w = pk2(b.z, b.w);
  return r;
}
template <>
__device__ __forceinline__ uint4 ld8ws_pk<u16>(const u16* p, size_t i) {
  return *(const uint4*)(p + i);
}

// B=4, S=1024, H=8, DH=64, D=512, NUM_RPR=11
// ws: [int flag][pad->1024B][qh|kh|vh], each [B*H=32][S=1024][64]
// NOTE (banked, rounds 6/7): LDS float atomicAdd for the RPR bins produced
// NaN output twice; bins MUST stay in registers.

// ---------------------------------------------------------------------------
// Kernel 0: dtype detector (validated rounds 2/4/5).
// ---------------------------------------------------------------------------
__global__ void rpr_detect_kernel(const u16* __restrict__ q, int* __restrict__ flag) {
  __shared__ int cnt[256];
  int t = threadIdx.x, c = 0;
  for (int i = t; i < 8192; i += 256) {
    unsigned e = (q[i] >> 7) & 0xff;
    c += (e >= 0xC0) ? 1 : 0;
  }
  cnt[t] = c;
  __syncthreads();
  if (t == 0) {
    int s = 0;
    for (int i = 0; i < 256; ++i) s += cnt[i];
    *flag = (s > 128) ? 1 : 0;
  }
}

// ---------------------------------------------------------------------------
// Kernel 1: QKV projection via bf16 MFMA — ROUND-8 CHANGE: 128x128 tile.
// Block 256 = 4 waves in a 2x2 quadrant grid; each wave computes a 64x64
// quadrant as 4x4 16x16 C-tiles (16 MFMA + 8 ds_read_b128 per BK=32 iter —
// the m97 amortization ratio). Frag/LDS layouts identical to the validated
// round-4/5 kernel; only thread-maps and quadrant indexing are new.
// ---------------------------------------------------------------------------
template <typename WT>
__global__ __launch_bounds__(256, 2) void rpr_proj_mfma(
    const void* __restrict__ xq, const void* __restrict__ xk, const void* __restrict__ xv,
    const void* __restrict__ wqp, const void* __restrict__ wkp, const void* __restrict__ wvp,
    const void* __restrict__ bqp, const void* __restrict__ bkp, const void* __restrict__ bvp,
    WT* __restrict__ ws, const int* __restrict__ flagp) {
  const bool f32 = (*flagp != 0);
  const int z = blockIdx.z;
  const void* __restrict__ X = (z == 0) ? xq : (z == 1) ? xk : xv;
  const void* __restrict__ W = (z == 0) ? wqp : (z == 1) ? wkp : wvp;
  const void* __restrict__ Bb = (z == 0) ? bqp : (z == 1) ? bkp : bvp;
  WT* __restrict__ O = ws + (size_t)z * (4096u * 512u);

  __shared__ u32 as32[128][20];  // A[m][k] bf16 u32-paired, u16 view [128][40]
  __shared__ u32 bs32[128][20];  // B^T[n][k] bf16 u32-paired

  const int t = threadIdx.x;
  const int wvi = t >> 6, lane = t & 63;
  const int quad = lane >> 4, col = lane & 15;
  const int wm = wvi >> 1, wn = wvi & 1;  // wave quadrant
  const int m0 = blockIdx.y * 128, n0 = blockIdx.x * 128;

  f32x4 acc[4][4];
#pragma unroll
  for (int i = 0; i < 4; ++i)
#pragma unroll
    for (int j = 0; j < 4; ++j) acc[i][j] = (f32x4){0.f, 0.f, 0.f, 0.f};

  for (int k0 = 0; k0 < 512; k0 += 32) {
    // stage A: thread -> row t>>1, k-chunk (t&1)*16 (two 8-elem groups)
    {
      int row = t >> 1, kc = (t & 1) * 16;
      float v[8];
      ld8in(X, (size_t)(m0 + row) * 512 + k0 + kc, f32, v);
      uint4 pk;
      pk.x = pk2(v[0], v[1]); pk.y = pk2(v[2], v[3]);
      pk.z = pk2(v[4], v[5]); pk.w = pk2(v[6], v[7]);
      *(uint4*)&as32[row][(t & 1) * 8] = pk;
      ld8in(X, (size_t)(m0 + row) * 512 + k0 + kc + 8, f32, v);
      pk.x = pk2(v[0], v[1]); pk.y = pk2(v[2], v[3]);
      pk.z = pk2(v[4], v[5]); pk.w = pk2(v[6], v[7]);
      *(uint4*)&as32[row][(t & 1) * 8 + 4] = pk;
    }
    // stage B^T via k-pair pack: kp = t&15, n-group (t>>4)*8
    {
      int kp = t & 15, nb = (t >> 4) * 8;
      size_t r0base = (size_t)(k0 + 2 * kp) * 512 + n0 + nb;
      size_t r1base = (size_t)(k0 + 2 * kp + 1) * 512 + n0 + nb;
      float4 r0a = ld4in(W, r0base, f32), r0b = ld4in(W, r0base + 4, f32);
      float4 r1a = ld4in(W, r1base, f32), r1b = ld4in(W, r1base + 4, f32);
      bs32[nb + 0][kp] = pk2(r0a.x, r1a.x);
      bs32[nb + 1][kp] = pk2(r0a.y, r1a.y);
      bs32[nb + 2][kp] = pk2(r0a.z, r1a.z);
      bs32[nb + 3][kp] = pk2(r0a.w, r1a.w);
      bs32[nb + 4][kp] = pk2(r0b.x, r1b.x);
      bs32[nb + 5][kp] = pk2(r0b.y, r1b.y);
      bs32[nb + 6][kp] = pk2(r0b.z, r1b.z);
      bs32[nb + 7][kp] = pk2(r0b.w, r1b.w);
    }
    __syncthreads();
    // A-frags: A[m=lane&15][k=quad*8+j] for 4 row-tiles of this quadrant
    short8 aF[4], bF[4];
#pragma unroll
    for (int i = 0; i < 4; ++i)
      aF[i] = *(const short8*)((const u16*)&as32[wm * 64 + i * 16 + col][0] + quad * 8);
#pragma unroll
    for (int j = 0; j < 4; ++j)
      bF[j] = *(const short8*)((const u16*)&bs32[wn * 64 + j * 16 + col][0] + quad * 8);
#pragma unroll
    for (int i = 0; i < 4; ++i)
#pragma unroll
      for (int j = 0; j < 4; ++j)
        acc[i][j] = __builtin_amdgcn_mfma_f32_16x16x32_bf16(aF[i], bF[j], acc[i][j], 0, 0, 0);
    __syncthreads();
  }

  // epilogue: bias + store to ws [bh][s][64]; cols n0+wn*64 span head
  // h = blockIdx.x*2 + wn, dh = j*16 + col
  const int h = blockIdx.x * 2 + wn;
#pragma unroll
  for (int j = 0; j < 4; ++j) {
    float bias = ld1in(Bb, (size_t)(n0 + wn * 64 + j * 16 + col), f32);
#pragma unroll
    for (int i = 0; i < 4; ++i) {
#pragma unroll
      for (int reg = 0; reg < 4; ++reg) {
        int m = m0 + wm * 64 + i * 16 + quad * 4 + reg;  // C: row = quad*4+reg
        int bb = m >> 10, s = m & 1023;
        st1ws(O, ((size_t)((bb * 8 + h) * 1024 + s)) * 64 + j * 16 + col,
              acc[i][j][reg] + bias);
      }
    }
  }
}

// ---------------------------------------------------------------------------
// Kernel 2: MFMA flash attention with RPR — round-5 validated, byte-identical.
// ---------------------------------------------------------------------------
template <typename WT>
__global__ __launch_bounds__(256, 2) void rpr_attn_mfma(
    const WT* __restrict__ qkv, const int* __restrict__ rpr,
    const void* __restrict__ krpr, void* __restrict__ out,
    const int* __restrict__ flagp) {
  const bool f32 = (*flagp != 0);
  const int bh = blockIdx.y, q0 = blockIdx.x * 64;
  const int b = bh >> 3, h = bh & 7;
  const WT* __restrict__ qh = qkv + (size_t)bh * 65536;
  const WT* __restrict__ kh = qkv + (size_t)(32 + bh) * 65536;
  const WT* __restrict__ vh = qkv + (size_t)(64 + bh) * 65536;

  __shared__ u16 qs[64][72];      // Q rows bf16 (stride 72)
  __shared__ u16 ks[64][72];      // K-tile [key][d]
  __shared__ u32 vs32[64][36];    // V^T [d][k-pair] u32-packed
  __shared__ u16 ps[4][16][72];   // per-wave P tile bf16 [q][k]
  __shared__ float krl[11][64];   // krpr fp32
  __shared__ float qrpr[64][12];  // q . krpr[r]
  __shared__ int rprt[64][68];    // rpr ids

  const int t = threadIdx.x;
  const int wvi = t >> 6, lane = t & 63;
  const int quad = lane >> 4, col = lane & 15;

  // ---- one-time staging ----
  for (int i = t; i < 704; i += 256)
    krl[i >> 6][i & 63] = f32 ? ((const float*)krpr)[i] : bf2f(((const u16*)krpr)[i]);
  {
    int r = t >> 2, c = (t & 3) * 16;
    size_t base = (size_t)(q0 + r) * 64 + c;
    *(uint4*)&qs[r][c] = ld8ws_pk(qh, base);
    *(uint4*)&qs[r][c + 8] = ld8ws_pk(qh, base + 8);
  }
  __syncthreads();
  // qrpr[row][r]: thread -> row t>>2, r in {t&3, +4, +8}
  {
    int r = t >> 2, rb = t & 3;
    float d0 = 0.f, d1 = 0.f, d2 = 0.f;
    for (int d = 0; d < 64; ++d) {
      float qv = bf2f(qs[r][d]);
      d0 = fmaf(qv, krl[rb][d], d0);
      d1 = fmaf(qv, krl[rb + 4][d], d1);
      if (rb < 3) d2 = fmaf(qv, krl[rb + 8][d], d2);
    }
    qrpr[r][rb] = d0;
    qrpr[r][rb + 4] = d1;
    if (rb < 3) qrpr[r][rb + 8] = d2;
  }
  // Q A-frags: A[m=lane&15][k=quad*8+j], two k-halves of DH=64
  short8 qA0, qA1;
  {
    const u16* qrow = &qs[wvi * 16 + col][0];
    qA0 = *(const short8*)(qrow + quad * 8);
    qA1 = *(const short8*)(qrow + 32 + quad * 8);
  }

  float l_part[4] = {0.f, 0.f, 0.f, 0.f};
  float bins[4][11] = {};  // [reg][r] — registers (LDS atomics are poison)
  f32x4 ctx[4] = {{0.f, 0.f, 0.f, 0.f}, {0.f, 0.f, 0.f, 0.f},
                  {0.f, 0.f, 0.f, 0.f}, {0.f, 0.f, 0.f, 0.f}};

  for (int kt = 0; kt < 16; ++kt) {
    const int k0 = kt * 64;
    // stage K [key][d]
    {
      int r = t >> 2, c = (t & 3) * 16;
      size_t base = (size_t)(k0 + r) * 64 + c;
      *(uint4*)&ks[r][c] = ld8ws_pk(kh, base);
      *(uint4*)&ks[r][c + 8] = ld8ws_pk(kh, base + 8);
    }
    // stage V^T [d][k] via k-pair packing
    {
      int kp = t & 31, dg = t >> 5;
      size_t base = (size_t)(k0 + 2 * kp) * 64 + dg * 8;
      float4 a0 = ld4ws(vh, base), a1 = ld4ws(vh, base + 4);
      float4 b0 = ld4ws(vh, base + 64), b1 = ld4ws(vh, base + 68);
      int d = dg * 8;
      vs32[d + 0][kp] = pk2(a0.x, b0.x);
      vs32[d + 1][kp] = pk2(a0.y, b0.y);
      vs32[d + 2][kp] = pk2(a0.z, b0.z);
      vs32[d + 3][kp] = pk2(a0.w, b0.w);
      vs32[d + 4][kp] = pk2(a1.x, b1.x);
      vs32[d + 5][kp] = pk2(a1.y, b1.y);
      vs32[d + 6][kp] = pk2(a1.z, b1.z);
      vs32[d + 7][kp] = pk2(a1.w, b1.w);
    }
    // stage rpr ids
    {
      int rr = t >> 4, cc = (t & 15) * 4;
#pragma unroll
      for (int i = 0; i < 4; ++i) {
        int4 rv = *(const int4*)(rpr + (size_t)(q0 + rr + 16 * i) * 1024 + k0 + cc);
        *(int4*)&rprt[rr + 16 * i][cc] = rv;
      }
    }
    __syncthreads();

    // ---- scores: QK^T via MFMA, 4 chunks of 16 keys ----
    f32x4 sc[4];
    int rid[4][4];
#pragma unroll
    for (int c = 0; c < 4; ++c) {
      const u16* kb = &ks[c * 16 + col][0];
      short8 kB0 = *(const short8*)(kb + quad * 8);
      short8 kB1 = *(const short8*)(kb + 32 + quad * 8);
      f32x4 a = {0.f, 0.f, 0.f, 0.f};
      a = __builtin_amdgcn_mfma_f32_16x16x32_bf16(qA0, kB0, a, 0, 0, 0);
      a = __builtin_amdgcn_mfma_f32_16x16x32_bf16(qA1, kB1, a, 0, 0, 0);
#pragma unroll
      for (int reg = 0; reg < 4; ++reg) {
        int row = wvi * 16 + quad * 4 + reg;  // block-local q row (C layout)
        int id = rprt[row][c * 16 + col];
        rid[c][reg] = id;
        a[reg] = (a[reg] + qrpr[row][id]) * 0.125f;  // 1/sqrt(64)
      }
      sc[c] = a;
    }
    // ---- p = exp(sc); accumulate l, bins; write P bf16 ----
#pragma unroll
    for (int c = 0; c < 4; ++c) {
#pragma unroll
      for (int reg = 0; reg < 4; ++reg) {
        float p = __expf(sc[c][reg]);
        l_part[reg] += p;
#pragma unroll
        for (int r = 0; r < 11; ++r) bins[reg][r] += (rid[c][reg] == r) ? p : 0.f;
        ps[wvi][quad * 4 + reg][c * 16 + col] = f2bf(p);
      }
    }
    __syncthreads();  // P visible for A-frag reads (validated round 5)

    // ---- PV: P (A-layout) x V^T rows (B-layout) ----
    short8 pA0, pA1;
    {
      const u16* prow = &ps[wvi][col][0];
      pA0 = *(const short8*)(prow + quad * 8);
      pA1 = *(const short8*)(prow + 32 + quad * 8);
    }
#pragma unroll
    for (int c = 0; c < 4; ++c) {
      const u16* vrow = (const u16*)&vs32[c * 16 + col][0];
      short8 vB0 = *(const short8*)(vrow + quad * 8);
      short8 vB1 = *(const short8*)(vrow + 32 + quad * 8);
      ctx[c] = __builtin_amdgcn_mfma_f32_16x16x32_bf16(pA0, vB0, ctx[c], 0, 0, 0);
      ctx[c] = __builtin_amdgcn_mfma_f32_16x16x32_bf16(pA1, vB1, ctx[c], 0, 0, 0);
    }
    __syncthreads();  // all tile reads done before next staging
  }

  // ---- epilogue: reduce l/bins over 16 lanes of each quad ----
#pragma unroll
  for (int off = 1; off < 16; off <<= 1) {
#pragma unroll
    for (int reg = 0; reg < 4; ++reg) {
      l_part[reg] += __shfl_xor(l_part[reg], off);
#pragma unroll
      for (int r = 0; r < 11; ++r) bins[reg][r] += __shfl_xor(bins[reg][r], off);
    }
  }
  // value-side RPR + normalize + store
#pragma unroll
  for (int reg = 0; reg < 4; ++reg) {
    int row = wvi * 16 + quad * 4 + reg;
    float inv = 1.f / l_part[reg];
#pragma unroll
    for (int c = 0; c < 4; ++c) {
      float v = ctx[c][reg];
#pragma unroll
      for (int r = 0; r < 11; ++r) v = fmaf(bins[reg][r], krl[r][c * 16 + col], v);
      size_t oidx = (size_t)(b * 1024 + q0 + row) * 512 + h * 64 + c * 16 + col;
      if (f32) ((float*)out)[oidx] = v * inv;
      else ((u16*)out)[oidx] = f2bf(v * inv);
    }
  }
}

// ---------------------------------------------------------------------------
extern "C" void kernel_launch(void* const* d_in, const int* in_sizes, int n_in,
                              void* d_out, int out_size, void* d_ws, size_t ws_size,
                              hipStream_t stream) {
  const void* q = d_in[0];
  const void* k = d_in[1];
  const void* v = d_in[2];
  const int* rpr = (const int*)d_in[3];
  const void* wq = d_in[4];
  const void* bq = d_in[5];
  const void* wk = d_in[6];
  const void* bk = d_in[7];
  const void* wv = d_in[8];
  const void* bv = d_in[9];
  const void* krpr = d_in[10];

  int* flag = (int*)d_ws;
  void* wsbase = (void*)((char*)d_ws + 1024);
  const size_t wselems = 3ull * 32 * 1024 * 64;  // 6,291,456

  rpr_detect_kernel<<<1, 256, 0, stream>>>((const u16*)q, flag);

  if (ws_size >= 1024 + wselems * 4) {  // fp32 ws path
    float* ws = (float*)wsbase;
    rpr_proj_mfma<float><<<dim3(4, 32, 3), 256, 0, stream>>>(
        q, k, v, wq, wk, wv, bq, bk, bv, ws, flag);
    rpr_attn_mfma<float><<<dim3(16, 32), 256, 0, stream>>>(
        ws, rpr, krpr, d_out, flag);
  } else {  // bf16 ws fallback
    u16* ws = (u16*)wsbase;
    rpr_proj_mfma<u16><<<dim3(4, 32, 3), 256, 0, stream>>>(
        q, k, v, wq, wk, wv, bq, bk, bv, ws, flag);
    rpr_attn_mfma<u16><<<dim3(16, 32), 256, 0, stream>>>(
        ws, rpr, krpr, d_out, flag);
  }
}

// Round 9
// 204.613 us; speedup vs baseline: 1.0811x; 1.0811x over previous
//
#include <hip/hip_runtime.h>

typedef unsigned short u16;
typedef unsigned int u32;
typedef __attribute__((ext_vector_type(8))) short short8;  // 8 bf16 (4 VGPRs)
typedef __attribute__((ext_vector_type(4))) float f32x4;   // MFMA acc

// ---- bf16 helpers ----
__device__ __forceinline__ float bf2f(u16 v) {
  return __uint_as_float(((u32)v) << 16);
}
__device__ __forceinline__ u16 f2bf(float f) {
  u32 u = __float_as_uint(f);
  return (u16)((u + 0x7fffu + ((u >> 16) & 1u)) >> 16);  // RNE
}
__device__ __forceinline__ u32 pk2(float lo, float hi) {
  return (u32)f2bf(lo) | ((u32)f2bf(hi) << 16);
}

// flagged input loads (fp32 vs bf16 decided at runtime, wave-uniform branch)
__device__ __forceinline__ float ld1in(const void* p, size_t i, bool f32) {
  return f32 ? ((const float*)p)[i] : bf2f(((const u16*)p)[i]);
}
__device__ __forceinline__ float4 ld4in(const void* p, size_t i, bool f32) {
  if (f32) return *(const float4*)((const float*)p + i);
  ushort4 u = *(const ushort4*)((const u16*)p + i);
  return make_float4(bf2f(u.x), bf2f(u.y), bf2f(u.z), bf2f(u.w));
}
__device__ __forceinline__ void ld8in(const void* p, size_t i, bool f32, float* v) {
  if (f32) {
    float4 a = *(const float4*)((const float*)p + i);
    float4 b = *(const float4*)((const float*)p + i + 4);
    v[0] = a.x; v[1] = a.y; v[2] = a.z; v[3] = a.w;
    v[4] = b.x; v[5] = b.y; v[6] = b.z; v[7] = b.w;
  } else {
    ushort4 a = *(const ushort4*)((const u16*)p + i);
    ushort4 b = *(const ushort4*)((const u16*)p + i + 4);
    v[0] = bf2f(a.x); v[1] = bf2f(a.y); v[2] = bf2f(a.z); v[3] = bf2f(a.w);
    v[4] = bf2f(b.x); v[5] = bf2f(b.y); v[6] = bf2f(b.z); v[7] = bf2f(b.w);
  }
}

// ws element store (dtype = template param) + loads
__device__ __forceinline__ void st1ws(float* p, size_t i, float v) { p[i] = v; }
__device__ __forceinline__ void st1ws(u16* p, size_t i, float v) { p[i] = f2bf(v); }
__device__ __forceinline__ float4 ld4ws(const float* p, size_t i) { return *(const float4*)(p + i); }
__device__ __forceinline__ float4 ld4ws(const u16* p, size_t i) {
  ushort4 u = *(const ushort4*)(p + i);
  return make_float4(bf2f(u.x), bf2f(u.y), bf2f(u.z), bf2f(u.w));
}
// 8 consecutive ws elems -> uint4 of bf16 pairs (identity copy on bf16 ws)
template <typename WT>
__device__ __forceinline__ uint4 ld8ws_pk(const WT* p, size_t i) {
  float4 a = ld4ws(p, i), b = ld4ws(p, i + 4);
  uint4 r;
  r.x = pk2(a.x, a.y); r.y = pk2(a.z, a.w);
  r.z = pk2(b.x, b.y); r.w = pk2(b.z, b.w);
  return r;
}
template <>
__device__ __forceinline__ uint4 ld8ws_pk<u16>(const u16* p, size_t i) {
  return *(const uint4*)(p + i);
}

// B=4, S=1024, H=8, DH=64, D=512, NUM_RPR=11
// ws: [int flag][pad->1024B][qh|kh|vh], each [B*H=32][S=1024][64]
// BANKED LESSONS: (rounds 6/7) LDS float atomicAdd bins -> NaN twice; bins
// stay in registers. (round 8) 128x128 proj tile neutral-to-worse (384-block
// imbalance); 64x64 x 1536 blocks is the validated proj shape.

// ---------------------------------------------------------------------------
// Kernel 0: dtype detector (validated rounds 2/4/5/8).
// ---------------------------------------------------------------------------
__global__ void rpr_detect_kernel(const u16* __restrict__ q, int* __restrict__ flag) {
  __shared__ int cnt[256];
  int t = threadIdx.x, c = 0;
  for (int i = t; i < 8192; i += 256) {
    unsigned e = (q[i] >> 7) & 0xff;
    c += (e >= 0xC0) ? 1 : 0;
  }
  cnt[t] = c;
  __syncthreads();
  if (t == 0) {
    int s = 0;
    for (int i = 0; i < 256; ++i) s += cnt[i];
    *flag = (s > 128) ? 1 : 0;
  }
}

// ---------------------------------------------------------------------------
// Kernel 1: QKV projection via bf16 MFMA (round-4/5 validated, 64x64, BK=32).
// ---------------------------------------------------------------------------
template <typename WT>
__global__ __launch_bounds__(256, 2) void rpr_proj_mfma(
    const void* __restrict__ xq, const void* __restrict__ xk, const void* __restrict__ xv,
    const void* __restrict__ wqp, const void* __restrict__ wkp, const void* __restrict__ wvp,
    const void* __restrict__ bqp, const void* __restrict__ bkp, const void* __restrict__ bvp,
    WT* __restrict__ ws, const int* __restrict__ flagp) {
  const bool f32 = (*flagp != 0);
  const int z = blockIdx.z;
  const void* __restrict__ X = (z == 0) ? xq : (z == 1) ? xk : xv;
  const void* __restrict__ W = (z == 0) ? wqp : (z == 1) ? wkp : wvp;
  const void* __restrict__ Bb = (z == 0) ? bqp : (z == 1) ? bkp : bvp;
  WT* __restrict__ O = ws + (size_t)z * (4096u * 512u);

  __shared__ u32 as32[64][20];  // A[m][k] bf16 u32-paired, u16 view [64][40]
  __shared__ u32 bs32[64][20];  // B^T[n][k] bf16 u32-paired

  const int t = threadIdx.x;
  const int wvi = t >> 6, lane = t & 63;
  const int quad = lane >> 4, col = lane & 15;
  const int m0 = blockIdx.y * 64, n0 = blockIdx.x * 64;

  f32x4 acc[4] = {{0.f, 0.f, 0.f, 0.f}, {0.f, 0.f, 0.f, 0.f},
                  {0.f, 0.f, 0.f, 0.f}, {0.f, 0.f, 0.f, 0.f}};

  for (int k0 = 0; k0 < 512; k0 += 32) {
    {
      int m = t >> 2, kc = (t & 3) * 8;
      float v[8];
      ld8in(X, (size_t)(m0 + m) * 512 + k0 + kc, f32, v);
      uint4 pk;
      pk.x = pk2(v[0], v[1]); pk.y = pk2(v[2], v[3]);
      pk.z = pk2(v[4], v[5]); pk.w = pk2(v[6], v[7]);
      *(uint4*)&as32[m][(t & 3) * 4] = pk;
    }
    {
      int kp = t & 15, nb = (t >> 4) * 4;
      float4 r0 = ld4in(W, (size_t)(k0 + 2 * kp) * 512 + n0 + nb, f32);
      float4 r1 = ld4in(W, (size_t)(k0 + 2 * kp + 1) * 512 + n0 + nb, f32);
      bs32[nb + 0][kp] = pk2(r0.x, r1.x);
      bs32[nb + 1][kp] = pk2(r0.y, r1.y);
      bs32[nb + 2][kp] = pk2(r0.z, r1.z);
      bs32[nb + 3][kp] = pk2(r0.w, r1.w);
    }
    __syncthreads();
    short8 aF = *(const short8*)((const u16*)&as32[wvi * 16 + col][0] + quad * 8);
#pragma unroll
    for (int c = 0; c < 4; ++c) {
      short8 bF = *(const short8*)((const u16*)&bs32[c * 16 + col][0] + quad * 8);
      acc[c] = __builtin_amdgcn_mfma_f32_16x16x32_bf16(aF, bF, acc[c], 0, 0, 0);
    }
    __syncthreads();
  }

  const int h = blockIdx.x;  // n0 >> 6
#pragma unroll
  for (int c = 0; c < 4; ++c) {
    float bias = ld1in(Bb, (size_t)(n0 + c * 16 + col), f32);
#pragma unroll
    for (int reg = 0; reg < 4; ++reg) {
      int m = m0 + wvi * 16 + quad * 4 + reg;  // C layout: row = quad*4+reg
      int bb = m >> 10, s = m & 1023;
      st1ws(O, ((size_t)((bb * 8 + h) * 1024 + s)) * 64 + c * 16 + col,
            acc[c][reg] + bias);
    }
  }
}

// ---------------------------------------------------------------------------
// Kernel 2: MFMA flash attention with RPR.
// ROUND-9 EXPERIMENT: K/V double-buffer with register prefetch (2 barriers/
// tile) + rid read directly from global (rprt LDS deleted; value-identical).
// All other mechanisms byte-identical to the round-5/8 validated kernel.
// ---------------------------------------------------------------------------
template <typename WT>
__global__ __launch_bounds__(256, 2) void rpr_attn_mfma(
    const WT* __restrict__ qkv, const int* __restrict__ rpr,
    const void* __restrict__ krpr, void* __restrict__ out,
    const int* __restrict__ flagp) {
  const bool f32 = (*flagp != 0);
  const int bh = blockIdx.y, q0 = blockIdx.x * 64;
  const int b = bh >> 3, h = bh & 7;
  const WT* __restrict__ qh = qkv + (size_t)bh * 65536;
  const WT* __restrict__ kh = qkv + (size_t)(32 + bh) * 65536;
  const WT* __restrict__ vh = qkv + (size_t)(64 + bh) * 65536;

  __shared__ u16 qs[64][72];       // Q rows bf16
  __shared__ u16 ks[2][64][72];    // K-tile [key][d], double-buffered
  __shared__ u32 vs32[2][64][36];  // V^T [d][k-pair] u32-packed, double-buffered
  __shared__ u16 ps[4][16][72];    // per-wave P tile bf16 [q][k]
  __shared__ float krl[11][64];    // krpr fp32
  __shared__ float qrpr[64][12];   // q . krpr[r]

  const int t = threadIdx.x;
  const int wvi = t >> 6, lane = t & 63;
  const int quad = lane >> 4, col = lane & 15;
  const int sr = t >> 2, sc4 = (t & 3) * 16;  // Q/K staging map
  const int kp = t & 31, dg = (t >> 5) * 8;   // V staging map

  // ---- one-time staging (krl, Q, K/V tile 0 -> buffer 0) ----
  for (int i = t; i < 704; i += 256)
    krl[i >> 6][i & 63] = f32 ? ((const float*)krpr)[i] : bf2f(((const u16*)krpr)[i]);
  {
    size_t base = (size_t)(q0 + sr) * 64 + sc4;
    *(uint4*)&qs[sr][sc4] = ld8ws_pk(qh, base);
    *(uint4*)&qs[sr][sc4 + 8] = ld8ws_pk(qh, base + 8);
  }
  {
    size_t kb = (size_t)sr * 64 + sc4;
    *(uint4*)&ks[0][sr][sc4] = ld8ws_pk(kh, kb);
    *(uint4*)&ks[0][sr][sc4 + 8] = ld8ws_pk(kh, kb + 8);
    size_t vb = (size_t)(2 * kp) * 64 + dg;
    uint4 va = ld8ws_pk(vh, vb), vbb = ld8ws_pk(vh, vb + 64);
    vs32[0][dg + 0][kp] = (va.x & 0xffffu) | (vbb.x << 16);
    vs32[0][dg + 1][kp] = (va.x >> 16) | (vbb.x & 0xffff0000u);
    vs32[0][dg + 2][kp] = (va.y & 0xffffu) | (vbb.y << 16);
    vs32[0][dg + 3][kp] = (va.y >> 16) | (vbb.y & 0xffff0000u);
    vs32[0][dg + 4][kp] = (va.z & 0xffffu) | (vbb.z << 16);
    vs32[0][dg + 5][kp] = (va.z >> 16) | (vbb.z & 0xffff0000u);
    vs32[0][dg + 6][kp] = (va.w & 0xffffu) | (vbb.w << 16);
    vs32[0][dg + 7][kp] = (va.w >> 16) | (vbb.w & 0xffff0000u);
  }
  __syncthreads();
  // qrpr[row][r]: thread -> row t>>2, r in {t&3, +4, +8}
  {
    int r = t >> 2, rb = t & 3;
    float d0 = 0.f, d1 = 0.f, d2 = 0.f;
    for (int d = 0; d < 64; ++d) {
      float qv = bf2f(qs[r][d]);
      d0 = fmaf(qv, krl[rb][d], d0);
      d1 = fmaf(qv, krl[rb + 4][d], d1);
      if (rb < 3) d2 = fmaf(qv, krl[rb + 8][d], d2);
    }
    qrpr[r][rb] = d0;
    qrpr[r][rb + 4] = d1;
    if (rb < 3) qrpr[r][rb + 8] = d2;
  }
  // Q A-frags: A[m=lane&15][k=quad*8+j], two k-halves of DH=64
  short8 qA0, qA1;
  {
    const u16* qrow = &qs[wvi * 16 + col][0];
    qA0 = *(const short8*)(qrow + quad * 8);
    qA1 = *(const short8*)(qrow + 32 + quad * 8);
  }
  __syncthreads();  // qrpr visible to all before first tile's softmax

  float l_part[4] = {0.f, 0.f, 0.f, 0.f};
  float bins[4][11] = {};  // registers (LDS atomics are poison — rounds 6/7)
  f32x4 ctx[4] = {{0.f, 0.f, 0.f, 0.f}, {0.f, 0.f, 0.f, 0.f},
                  {0.f, 0.f, 0.f, 0.f}, {0.f, 0.f, 0.f, 0.f}};

  for (int kt = 0; kt < 16; ++kt) {
    const int cur = kt & 1;
    // (A) prefetch next K/V tile into registers (latency hidden under B-E)
    uint4 pk0, pk1, pva, pvb;
    if (kt < 15) {
      size_t kb = (size_t)((kt + 1) * 64 + sr) * 64 + sc4;
      pk0 = ld8ws_pk(kh, kb);
      pk1 = ld8ws_pk(kh, kb + 8);
      size_t vb = (size_t)((kt + 1) * 64 + 2 * kp) * 64 + dg;
      pva = ld8ws_pk(vh, vb);
      pvb = ld8ws_pk(vh, vb + 64);
    }
    // rid direct from global (L2-hot; value-identical to the old rprt path)
    int rid[4][4];
    {
      const int* rbase =
          rpr + (size_t)(q0 + wvi * 16 + quad * 4) * 1024 + kt * 64 + col;
#pragma unroll
      for (int reg = 0; reg < 4; ++reg)
#pragma unroll
        for (int c = 0; c < 4; ++c) rid[c][reg] = rbase[reg * 1024 + c * 16];
    }
    // (B) scores: QK^T via MFMA, 4 chunks of 16 keys
    f32x4 sc[4];
#pragma unroll
    for (int c = 0; c < 4; ++c) {
      const u16* kb = &ks[cur][c * 16 + col][0];
      short8 kB0 = *(const short8*)(kb + quad * 8);
      short8 kB1 = *(const short8*)(kb + 32 + quad * 8);
      f32x4 a = {0.f, 0.f, 0.f, 0.f};
      a = __builtin_amdgcn_mfma_f32_16x16x32_bf16(qA0, kB0, a, 0, 0, 0);
      a = __builtin_amdgcn_mfma_f32_16x16x32_bf16(qA1, kB1, a, 0, 0, 0);
      sc[c] = a;
    }
    // (C) p = exp((s + rpr-bias)/8); accumulate l, register bins; write P bf16
#pragma unroll
    for (int c = 0; c < 4; ++c) {
#pragma unroll
      for (int reg = 0; reg < 4; ++reg) {
        int row = wvi * 16 + quad * 4 + reg;  // C layout: row = quad*4+reg
        float p = __expf((sc[c][reg] + qrpr[row][rid[c][reg]]) * 0.125f);
        l_part[reg] += p;
#pragma unroll
        for (int r = 0; r < 11; ++r) bins[reg][r] += (rid[c][reg] == r) ? p : 0.f;
        ps[wvi][quad * 4 + reg][c * 16 + col] = f2bf(p);
      }
    }
    __syncthreads();  // P visible for A-frag reads (validated round 5)

    // (D) PV: P (A-layout) x V^T rows (B-layout)
    short8 pA0, pA1;
    {
      const u16* prow = &ps[wvi][col][0];
      pA0 = *(const short8*)(prow + quad * 8);
      pA1 = *(const short8*)(prow + 32 + quad * 8);
    }
#pragma unroll
    for (int c = 0; c < 4; ++c) {
      const u16* vrow = (const u16*)&vs32[cur][c * 16 + col][0];
      short8 vB0 = *(const short8*)(vrow + quad * 8);
      short8 vB1 = *(const short8*)(vrow + 32 + quad * 8);
      ctx[c] = __builtin_amdgcn_mfma_f32_16x16x32_bf16(pA0, vB0, ctx[c], 0, 0, 0);
      ctx[c] = __builtin_amdgcn_mfma_f32_16x16x32_bf16(pA1, vB1, ctx[c], 0, 0, 0);
    }
    // (E) write prefetched tile into the alternate buffer
    if (kt < 15) {
      *(uint4*)&ks[1 - cur][sr][sc4] = pk0;
      *(uint4*)&ks[1 - cur][sr][sc4 + 8] = pk1;
      vs32[1 - cur][dg + 0][kp] = (pva.x & 0xffffu) | (pvb.x << 16);
      vs32[1 - cur][dg + 1][kp] = (pva.x >> 16) | (pvb.x & 0xffff0000u);
      vs32[1 - cur][dg + 2][kp] = (pva.y & 0xffffu) | (pvb.y << 16);
      vs32[1 - cur][dg + 3][kp] = (pva.y >> 16) | (pvb.y & 0xffff0000u);
      vs32[1 - cur][dg + 4][kp] = (pva.z & 0xffffu) | (pvb.z << 16);
      vs32[1 - cur][dg + 5][kp] = (pva.z >> 16) | (pvb.z & 0xffff0000u);
      vs32[1 - cur][dg + 6][kp] = (pva.w & 0xffffu) | (pvb.w << 16);
      vs32[1 - cur][dg + 7][kp] = (pva.w >> 16) | (pvb.w & 0xffff0000u);
    }
    __syncthreads();  // next tile's frag reads see the new buffer
  }

  // ---- epilogue: reduce l/bins over 16 lanes of each quad ----
#pragma unroll
  for (int off = 1; off < 16; off <<= 1) {
#pragma unroll
    for (int reg = 0; reg < 4; ++reg) {
      l_part[reg] += __shfl_xor(l_part[reg], off);
#pragma unroll
      for (int r = 0; r < 11; ++r) bins[reg][r] += __shfl_xor(bins[reg][r], off);
    }
  }
  // value-side RPR + normalize + store
#pragma unroll
  for (int reg = 0; reg < 4; ++reg) {
    int row = wvi * 16 + quad * 4 + reg;
    float inv = 1.f / l_part[reg];
#pragma unroll
    for (int c = 0; c < 4; ++c) {
      float v = ctx[c][reg];
#pragma unroll
      for (int r = 0; r < 11; ++r) v = fmaf(bins[reg][r], krl[r][c * 16 + col], v);
      size_t oidx = (size_t)(b * 1024 + q0 + row) * 512 + h * 64 + c * 16 + col;
      if (f32) ((float*)out)[oidx] = v * inv;
      else ((u16*)out)[oidx] = f2bf(v * inv);
    }
  }
}

// ---------------------------------------------------------------------------
extern "C" void kernel_launch(void* const* d_in, const int* in_sizes, int n_in,
                              void* d_out, int out_size, void* d_ws, size_t ws_size,
                              hipStream_t stream) {
  const void* q = d_in[0];
  const void* k = d_in[1];
  const void* v = d_in[2];
  const int* rpr = (const int*)d_in[3];
  const void* wq = d_in[4];
  const void* bq = d_in[5];
  const void* wk = d_in[6];
  const void* bk = d_in[7];
  const void* wv = d_in[8];
  const void* bv = d_in[9];
  const void* krpr = d_in[10];

  int* flag = (int*)d_ws;
  void* wsbase = (void*)((char*)d_ws + 1024);
  const size_t wselems = 3ull * 32 * 1024 * 64;  // 6,291,456

  rpr_detect_kernel<<<1, 256, 0, stream>>>((const u16*)q, flag);

  if (ws_size >= 1024 + wselems * 4) {  // fp32 ws path
    float* ws = (float*)wsbase;
    rpr_proj_mfma<float><<<dim3(8, 64, 3), 256, 0, stream>>>(
        q, k, v, wq, wk, wv, bq, bk, bv, ws, flag);
    rpr_attn_mfma<float><<<dim3(16, 32), 256, 0, stream>>>(
        ws, rpr, krpr, d_out, flag);
  } else {  // bf16 ws fallback
    u16* ws = (u16*)wsbase;
    rpr_proj_mfma<u16><<<dim3(8, 64, 3), 256, 0, stream>>>(
        q, k, v, wq, wk, wv, bq, bk, bv, ws, flag);
    rpr_attn_mfma<u16><<<dim3(16, 32), 256, 0, stream>>>(
        ws, rpr, krpr, d_out, flag);
  }
}

// Round 10
// 191.604 us; speedup vs baseline: 1.1545x; 1.0679x over previous
//
#include <hip/hip_runtime.h>

typedef unsigned short u16;
typedef unsigned int u32;
typedef __attribute__((ext_vector_type(8))) short short8;  // 8 bf16 (4 VGPRs)
typedef __attribute__((ext_vector_type(4))) float f32x4;   // MFMA acc

// ---- bf16 helpers ----
__device__ __forceinline__ float bf2f(u16 v) {
  return __uint_as_float(((u32)v) << 16);
}
__device__ __forceinline__ u16 f2bf(float f) {
  u32 u = __float_as_uint(f);
  return (u16)((u + 0x7fffu + ((u >> 16) & 1u)) >> 16);  // RNE
}
__device__ __forceinline__ u32 pk2(float lo, float hi) {
  return (u32)f2bf(lo) | ((u32)f2bf(hi) << 16);
}

// flagged input loads (fp32 vs bf16 decided at runtime, wave-uniform branch)
__device__ __forceinline__ float ld1in(const void* p, size_t i, bool f32) {
  return f32 ? ((const float*)p)[i] : bf2f(((const u16*)p)[i]);
}
__device__ __forceinline__ float4 ld4in(const void* p, size_t i, bool f32) {
  if (f32) return *(const float4*)((const float*)p + i);
  ushort4 u = *(const ushort4*)((const u16*)p + i);
  return make_float4(bf2f(u.x), bf2f(u.y), bf2f(u.z), bf2f(u.w));
}
__device__ __forceinline__ void ld8in(const void* p, size_t i, bool f32, float* v) {
  if (f32) {
    float4 a = *(const float4*)((const float*)p + i);
    float4 b = *(const float4*)((const float*)p + i + 4);
    v[0] = a.x; v[1] = a.y; v[2] = a.z; v[3] = a.w;
    v[4] = b.x; v[5] = b.y; v[6] = b.z; v[7] = b.w;
  } else {
    ushort4 a = *(const ushort4*)((const u16*)p + i);
    ushort4 b = *(const ushort4*)((const u16*)p + i + 4);
    v[0] = bf2f(a.x); v[1] = bf2f(a.y); v[2] = bf2f(a.z); v[3] = bf2f(a.w);
    v[4] = bf2f(b.x); v[5] = bf2f(b.y); v[6] = bf2f(b.z); v[7] = bf2f(b.w);
  }
}

// ws element store (dtype = template param) + loads
__device__ __forceinline__ void st1ws(float* p, size_t i, float v) { p[i] = v; }
__device__ __forceinline__ void st1ws(u16* p, size_t i, float v) { p[i] = f2bf(v); }
__device__ __forceinline__ float4 ld4ws(const float* p, size_t i) { return *(const float4*)(p + i); }
__device__ __forceinline__ float4 ld4ws(const u16* p, size_t i) {
  ushort4 u = *(const ushort4*)(p + i);
  return make_float4(bf2f(u.x), bf2f(u.y), bf2f(u.z), bf2f(u.w));
}
// 8 consecutive ws elems -> uint4 of bf16 pairs (identity copy on bf16 ws)
template <typename WT>
__device__ __forceinline__ uint4 ld8ws_pk(const WT* p, size_t i) {
  float4 a = ld4ws(p, i), b = ld4ws(p, i + 4);
  uint4 r;
  r.x = pk2(a.x, a.y); r.y = pk2(a.z, a.w);
  r.z = pk2(b.x, b.y); r.w = pk2(b.z, b.w);
  return r;
}
template <>
__device__ __forceinline__ uint4 ld8ws_pk<u16>(const u16* p, size_t i) {
  return *(const uint4*)(p + i);
}

// B=4, S=1024, H=8, DH=64, D=512, NUM_RPR=11
// ws: [int flag][pad->1024B][qh|kh|vh] bf16, each [B*H=32][S=1024][64]
// BANKED LESSONS: (r6/7) LDS float atomicAdd bins -> NaN twice; bins stay in
// registers. (r8) 128x128 proj tile neutral-to-worse; 64x64 is the shape.
// (r9) K/V dbuf + rid-from-global validated, attn 98->86us.
// ROUND-10: ws forced to bf16 (u16 instantiation) — halves ws traffic and
// deletes the f2bf pack chains in attn staging IF the fp32-ws branch was the
// one running before (ws_size-selected, never observed).

// ---------------------------------------------------------------------------
// Kernel 0: dtype detector (validated rounds 2/4/5/8/9).
// ---------------------------------------------------------------------------
__global__ void rpr_detect_kernel(const u16* __restrict__ q, int* __restrict__ flag) {
  __shared__ int cnt[256];
  int t = threadIdx.x, c = 0;
  for (int i = t; i < 8192; i += 256) {
    unsigned e = (q[i] >> 7) & 0xff;
    c += (e >= 0xC0) ? 1 : 0;
  }
  cnt[t] = c;
  __syncthreads();
  if (t == 0) {
    int s = 0;
    for (int i = 0; i < 256; ++i) s += cnt[i];
    *flag = (s > 128) ? 1 : 0;
  }
}

// ---------------------------------------------------------------------------
// Kernel 1: QKV projection via bf16 MFMA (round-4/5/9 validated, 64x64, BK=32).
// ---------------------------------------------------------------------------
template <typename WT>
__global__ __launch_bounds__(256, 2) void rpr_proj_mfma(
    const void* __restrict__ xq, const void* __restrict__ xk, const void* __restrict__ xv,
    const void* __restrict__ wqp, const void* __restrict__ wkp, const void* __restrict__ wvp,
    const void* __restrict__ bqp, const void* __restrict__ bkp, const void* __restrict__ bvp,
    WT* __restrict__ ws, const int* __restrict__ flagp) {
  const bool f32 = (*flagp != 0);
  const int z = blockIdx.z;
  const void* __restrict__ X = (z == 0) ? xq : (z == 1) ? xk : xv;
  const void* __restrict__ W = (z == 0) ? wqp : (z == 1) ? wkp : wvp;
  const void* __restrict__ Bb = (z == 0) ? bqp : (z == 1) ? bkp : bvp;
  WT* __restrict__ O = ws + (size_t)z * (4096u * 512u);

  __shared__ u32 as32[64][20];  // A[m][k] bf16 u32-paired, u16 view [64][40]
  __shared__ u32 bs32[64][20];  // B^T[n][k] bf16 u32-paired

  const int t = threadIdx.x;
  const int wvi = t >> 6, lane = t & 63;
  const int quad = lane >> 4, col = lane & 15;
  const int m0 = blockIdx.y * 64, n0 = blockIdx.x * 64;

  f32x4 acc[4] = {{0.f, 0.f, 0.f, 0.f}, {0.f, 0.f, 0.f, 0.f},
                  {0.f, 0.f, 0.f, 0.f}, {0.f, 0.f, 0.f, 0.f}};

  for (int k0 = 0; k0 < 512; k0 += 32) {
    {
      int m = t >> 2, kc = (t & 3) * 8;
      float v[8];
      ld8in(X, (size_t)(m0 + m) * 512 + k0 + kc, f32, v);
      uint4 pk;
      pk.x = pk2(v[0], v[1]); pk.y = pk2(v[2], v[3]);
      pk.z = pk2(v[4], v[5]); pk.w = pk2(v[6], v[7]);
      *(uint4*)&as32[m][(t & 3) * 4] = pk;
    }
    {
      int kp = t & 15, nb = (t >> 4) * 4;
      float4 r0 = ld4in(W, (size_t)(k0 + 2 * kp) * 512 + n0 + nb, f32);
      float4 r1 = ld4in(W, (size_t)(k0 + 2 * kp + 1) * 512 + n0 + nb, f32);
      bs32[nb + 0][kp] = pk2(r0.x, r1.x);
      bs32[nb + 1][kp] = pk2(r0.y, r1.y);
      bs32[nb + 2][kp] = pk2(r0.z, r1.z);
      bs32[nb + 3][kp] = pk2(r0.w, r1.w);
    }
    __syncthreads();
    short8 aF = *(const short8*)((const u16*)&as32[wvi * 16 + col][0] + quad * 8);
#pragma unroll
    for (int c = 0; c < 4; ++c) {
      short8 bF = *(const short8*)((const u16*)&bs32[c * 16 + col][0] + quad * 8);
      acc[c] = __builtin_amdgcn_mfma_f32_16x16x32_bf16(aF, bF, acc[c], 0, 0, 0);
    }
    __syncthreads();
  }

  const int h = blockIdx.x;  // n0 >> 6
#pragma unroll
  for (int c = 0; c < 4; ++c) {
    float bias = ld1in(Bb, (size_t)(n0 + c * 16 + col), f32);
#pragma unroll
    for (int reg = 0; reg < 4; ++reg) {
      int m = m0 + wvi * 16 + quad * 4 + reg;  // C layout: row = quad*4+reg
      int bb = m >> 10, s = m & 1023;
      st1ws(O, ((size_t)((bb * 8 + h) * 1024 + s)) * 64 + c * 16 + col,
            acc[c][reg] + bias);
    }
  }
}

// ---------------------------------------------------------------------------
// Kernel 2: MFMA flash attention with RPR (round-9 validated: K/V dbuf with
// register prefetch, 2 barriers/tile, rid from global, register bins).
// ---------------------------------------------------------------------------
template <typename WT>
__global__ __launch_bounds__(256, 2) void rpr_attn_mfma(
    const WT* __restrict__ qkv, const int* __restrict__ rpr,
    const void* __restrict__ krpr, void* __restrict__ out,
    const int* __restrict__ flagp) {
  const bool f32 = (*flagp != 0);
  const int bh = blockIdx.y, q0 = blockIdx.x * 64;
  const int b = bh >> 3, h = bh & 7;
  const WT* __restrict__ qh = qkv + (size_t)bh * 65536;
  const WT* __restrict__ kh = qkv + (size_t)(32 + bh) * 65536;
  const WT* __restrict__ vh = qkv + (size_t)(64 + bh) * 65536;

  __shared__ u16 qs[64][72];       // Q rows bf16
  __shared__ u16 ks[2][64][72];    // K-tile [key][d], double-buffered
  __shared__ u32 vs32[2][64][36];  // V^T [d][k-pair] u32-packed, double-buffered
  __shared__ u16 ps[4][16][72];    // per-wave P tile bf16 [q][k]
  __shared__ float krl[11][64];    // krpr fp32
  __shared__ float qrpr[64][12];   // q . krpr[r]

  const int t = threadIdx.x;
  const int wvi = t >> 6, lane = t & 63;
  const int quad = lane >> 4, col = lane & 15;
  const int sr = t >> 2, sc4 = (t & 3) * 16;  // Q/K staging map
  const int kp = t & 31, dg = (t >> 5) * 8;   // V staging map

  // ---- one-time staging (krl, Q, K/V tile 0 -> buffer 0) ----
  for (int i = t; i < 704; i += 256)
    krl[i >> 6][i & 63] = f32 ? ((const float*)krpr)[i] : bf2f(((const u16*)krpr)[i]);
  {
    size_t base = (size_t)(q0 + sr) * 64 + sc4;
    *(uint4*)&qs[sr][sc4] = ld8ws_pk(qh, base);
    *(uint4*)&qs[sr][sc4 + 8] = ld8ws_pk(qh, base + 8);
  }
  {
    size_t kb = (size_t)sr * 64 + sc4;
    *(uint4*)&ks[0][sr][sc4] = ld8ws_pk(kh, kb);
    *(uint4*)&ks[0][sr][sc4 + 8] = ld8ws_pk(kh, kb + 8);
    size_t vb = (size_t)(2 * kp) * 64 + dg;
    uint4 va = ld8ws_pk(vh, vb), vbb = ld8ws_pk(vh, vb + 64);
    vs32[0][dg + 0][kp] = (va.x & 0xffffu) | (vbb.x << 16);
    vs32[0][dg + 1][kp] = (va.x >> 16) | (vbb.x & 0xffff0000u);
    vs32[0][dg + 2][kp] = (va.y & 0xffffu) | (vbb.y << 16);
    vs32[0][dg + 3][kp] = (va.y >> 16) | (vbb.y & 0xffff0000u);
    vs32[0][dg + 4][kp] = (va.z & 0xffffu) | (vbb.z << 16);
    vs32[0][dg + 5][kp] = (va.z >> 16) | (vbb.z & 0xffff0000u);
    vs32[0][dg + 6][kp] = (va.w & 0xffffu) | (vbb.w << 16);
    vs32[0][dg + 7][kp] = (va.w >> 16) | (vbb.w & 0xffff0000u);
  }
  __syncthreads();
  // qrpr[row][r]: thread -> row t>>2, r in {t&3, +4, +8}
  {
    int r = t >> 2, rb = t & 3;
    float d0 = 0.f, d1 = 0.f, d2 = 0.f;
    for (int d = 0; d < 64; ++d) {
      float qv = bf2f(qs[r][d]);
      d0 = fmaf(qv, krl[rb][d], d0);
      d1 = fmaf(qv, krl[rb + 4][d], d1);
      if (rb < 3) d2 = fmaf(qv, krl[rb + 8][d], d2);
    }
    qrpr[r][rb] = d0;
    qrpr[r][rb + 4] = d1;
    if (rb < 3) qrpr[r][rb + 8] = d2;
  }
  // Q A-frags: A[m=lane&15][k=quad*8+j], two k-halves of DH=64
  short8 qA0, qA1;
  {
    const u16* qrow = &qs[wvi * 16 + col][0];
    qA0 = *(const short8*)(qrow + quad * 8);
    qA1 = *(const short8*)(qrow + 32 + quad * 8);
  }
  __syncthreads();  // qrpr visible to all before first tile's softmax

  float l_part[4] = {0.f, 0.f, 0.f, 0.f};
  float bins[4][11] = {};  // registers (LDS atomics are poison — rounds 6/7)
  f32x4 ctx[4] = {{0.f, 0.f, 0.f, 0.f}, {0.f, 0.f, 0.f, 0.f},
                  {0.f, 0.f, 0.f, 0.f}, {0.f, 0.f, 0.f, 0.f}};

  for (int kt = 0; kt < 16; ++kt) {
    const int cur = kt & 1;
    // (A) prefetch next K/V tile into registers (latency hidden under B-E)
    uint4 pk0, pk1, pva, pvb;
    if (kt < 15) {
      size_t kb = (size_t)((kt + 1) * 64 + sr) * 64 + sc4;
      pk0 = ld8ws_pk(kh, kb);
      pk1 = ld8ws_pk(kh, kb + 8);
      size_t vb = (size_t)((kt + 1) * 64 + 2 * kp) * 64 + dg;
      pva = ld8ws_pk(vh, vb);
      pvb = ld8ws_pk(vh, vb + 64);
    }
    // rid direct from global (L2-hot; validated round 9)
    int rid[4][4];
    {
      const int* rbase =
          rpr + (size_t)(q0 + wvi * 16 + quad * 4) * 1024 + kt * 64 + col;
#pragma unroll
      for (int reg = 0; reg < 4; ++reg)
#pragma unroll
        for (int c = 0; c < 4; ++c) rid[c][reg] = rbase[reg * 1024 + c * 16];
    }
    // (B) scores: QK^T via MFMA, 4 chunks of 16 keys
    f32x4 sc[4];
#pragma unroll
    for (int c = 0; c < 4; ++c) {
      const u16* kb = &ks[cur][c * 16 + col][0];
      short8 kB0 = *(const short8*)(kb + quad * 8);
      short8 kB1 = *(const short8*)(kb + 32 + quad * 8);
      f32x4 a = {0.f, 0.f, 0.f, 0.f};
      a = __builtin_amdgcn_mfma_f32_16x16x32_bf16(qA0, kB0, a, 0, 0, 0);
      a = __builtin_amdgcn_mfma_f32_16x16x32_bf16(qA1, kB1, a, 0, 0, 0);
      sc[c] = a;
    }
    // (C) p = exp((s + rpr-bias)/8); accumulate l, register bins; write P bf16
#pragma unroll
    for (int c = 0; c < 4; ++c) {
#pragma unroll
      for (int reg = 0; reg < 4; ++reg) {
        int row = wvi * 16 + quad * 4 + reg;  // C layout: row = quad*4+reg
        float p = __expf((sc[c][reg] + qrpr[row][rid[c][reg]]) * 0.125f);
        l_part[reg] += p;
#pragma unroll
        for (int r = 0; r < 11; ++r) bins[reg][r] += (rid[c][reg] == r) ? p : 0.f;
        ps[wvi][quad * 4 + reg][c * 16 + col] = f2bf(p);
      }
    }
    __syncthreads();  // P visible for A-frag reads (validated round 5)

    // (D) PV: P (A-layout) x V^T rows (B-layout)
    short8 pA0, pA1;
    {
      const u16* prow = &ps[wvi][col][0];
      pA0 = *(const short8*)(prow + quad * 8);
      pA1 = *(const short8*)(prow + 32 + quad * 8);
    }
#pragma unroll
    for (int c = 0; c < 4; ++c) {
      const u16* vrow = (const u16*)&vs32[cur][c * 16 + col][0];
      short8 vB0 = *(const short8*)(vrow + quad * 8);
      short8 vB1 = *(const short8*)(vrow + 32 + quad * 8);
      ctx[c] = __builtin_amdgcn_mfma_f32_16x16x32_bf16(pA0, vB0, ctx[c], 0, 0, 0);
      ctx[c] = __builtin_amdgcn_mfma_f32_16x16x32_bf16(pA1, vB1, ctx[c], 0, 0, 0);
    }
    // (E) write prefetched tile into the alternate buffer
    if (kt < 15) {
      *(uint4*)&ks[1 - cur][sr][sc4] = pk0;
      *(uint4*)&ks[1 - cur][sr][sc4 + 8] = pk1;
      vs32[1 - cur][dg + 0][kp] = (pva.x & 0xffffu) | (pvb.x << 16);
      vs32[1 - cur][dg + 1][kp] = (pva.x >> 16) | (pvb.x & 0xffff0000u);
      vs32[1 - cur][dg + 2][kp] = (pva.y & 0xffffu) | (pvb.y << 16);
      vs32[1 - cur][dg + 3][kp] = (pva.y >> 16) | (pvb.y & 0xffff0000u);
      vs32[1 - cur][dg + 4][kp] = (pva.z & 0xffffu) | (pvb.z << 16);
      vs32[1 - cur][dg + 5][kp] = (pva.z >> 16) | (pvb.z & 0xffff0000u);
      vs32[1 - cur][dg + 6][kp] = (pva.w & 0xffffu) | (pvb.w << 16);
      vs32[1 - cur][dg + 7][kp] = (pva.w >> 16) | (pvb.w & 0xffff0000u);
    }
    __syncthreads();  // next tile's frag reads see the new buffer
  }

  // ---- epilogue: reduce l/bins over 16 lanes of each quad ----
#pragma unroll
  for (int off = 1; off < 16; off <<= 1) {
#pragma unroll
    for (int reg = 0; reg < 4; ++reg) {
      l_part[reg] += __shfl_xor(l_part[reg], off);
#pragma unroll
      for (int r = 0; r < 11; ++r) bins[reg][r] += __shfl_xor(bins[reg][r], off);
    }
  }
  // value-side RPR + normalize + store
#pragma unroll
  for (int reg = 0; reg < 4; ++reg) {
    int row = wvi * 16 + quad * 4 + reg;
    float inv = 1.f / l_part[reg];
#pragma unroll
    for (int c = 0; c < 4; ++c) {
      float v = ctx[c][reg];
#pragma unroll
      for (int r = 0; r < 11; ++r) v = fmaf(bins[reg][r], krl[r][c * 16 + col], v);
      size_t oidx = (size_t)(b * 1024 + q0 + row) * 512 + h * 64 + c * 16 + col;
      if (f32) ((float*)out)[oidx] = v * inv;
      else ((u16*)out)[oidx] = f2bf(v * inv);
    }
  }
}

// ---------------------------------------------------------------------------
extern "C" void kernel_launch(void* const* d_in, const int* in_sizes, int n_in,
                              void* d_out, int out_size, void* d_ws, size_t ws_size,
                              hipStream_t stream) {
  const void* q = d_in[0];
  const void* k = d_in[1];
  const void* v = d_in[2];
  const int* rpr = (const int*)d_in[3];
  const void* wq = d_in[4];
  const void* bq = d_in[5];
  const void* wk = d_in[6];
  const void* bk = d_in[7];
  const void* wv = d_in[8];
  const void* bv = d_in[9];
  const void* krpr = d_in[10];

  int* flag = (int*)d_ws;
  u16* ws = (u16*)((char*)d_ws + 1024);  // bf16 ws: 12.6 MB (forced this round)

  rpr_detect_kernel<<<1, 256, 0, stream>>>((const u16*)q, flag);
  rpr_proj_mfma<u16><<<dim3(8, 64, 3), 256, 0, stream>>>(
      q, k, v, wq, wk, wv, bq, bk, bv, ws, flag);
  rpr_attn_mfma<u16><<<dim3(16, 32), 256, 0, stream>>>(
      ws, rpr, krpr, d_out, flag);
}

// Round 12
// 190.919 us; speedup vs baseline: 1.1586x; 1.0036x over previous
//
#include <hip/hip_runtime.h>

typedef unsigned short u16;
typedef unsigned int u32;
typedef __attribute__((ext_vector_type(8))) short short8;  // 8 bf16 (4 VGPRs)
typedef __attribute__((ext_vector_type(4))) float f32x4;   // MFMA acc

// ---- bf16 helpers ----
__device__ __forceinline__ float bf2f(u16 v) {
  return __uint_as_float(((u32)v) << 16);
}
__device__ __forceinline__ u16 f2bf(float f) {
  u32 u = __float_as_uint(f);
  return (u16)((u + 0x7fffu + ((u >> 16) & 1u)) >> 16);  // RNE
}
__device__ __forceinline__ u32 pk2(float lo, float hi) {
  return (u32)f2bf(lo) | ((u32)f2bf(hi) << 16);
}

// flagged input loads (fp32 vs bf16 decided at runtime, wave-uniform branch)
__device__ __forceinline__ float ld1in(const void* p, size_t i, bool f32) {
  return f32 ? ((const float*)p)[i] : bf2f(((const u16*)p)[i]);
}
__device__ __forceinline__ float4 ld4in(const void* p, size_t i, bool f32) {
  if (f32) return *(const float4*)((const float*)p + i);
  ushort4 u = *(const ushort4*)((const u16*)p + i);
  return make_float4(bf2f(u.x), bf2f(u.y), bf2f(u.z), bf2f(u.w));
}

// ws loads (ws is bf16 — forced since round 10)
__device__ __forceinline__ float4 ld4ws(const u16* p, size_t i) {
  ushort4 u = *(const ushort4*)(p + i);
  return make_float4(bf2f(u.x), bf2f(u.y), bf2f(u.z), bf2f(u.w));
}
__device__ __forceinline__ uint4 ld8ws_pk(const u16* p, size_t i) {
  return *(const uint4*)(p + i);
}

// B=4, S=1024, H=8, DH=64, D=512, NUM_RPR=11
// ws: [int flag][pad->1024B][qh|kh|vh] bf16, each [B*H=32][S=1024][64]
// BANKED LESSONS: (r6/7) LDS float atomicAdd bins -> NaN twice; bins stay in
// registers. (r8) 128x128 proj tile neutral-to-worse; 64x64 is the shape.
// (r9) attn K/V dbuf + rid-from-global validated, attn 98->86us.
// (r10) fp32-ws path had been running; bf16 ws forced: attn 86->72us.
// (r11) COMPILE FAIL: local cannot shadow a function parameter (bkp) in the
// outermost block — renamed staging locals this round.

// ---------------------------------------------------------------------------
// Kernel 0: dtype detector (validated rounds 2/4/5/8/9/10).
// ---------------------------------------------------------------------------
__global__ void rpr_detect_kernel(const u16* __restrict__ q, int* __restrict__ flag) {
  __shared__ int cnt[256];
  int t = threadIdx.x, c = 0;
  for (int i = t; i < 8192; i += 256) {
    unsigned e = (q[i] >> 7) & 0xff;
    c += (e >= 0xC0) ? 1 : 0;
  }
  cnt[t] = c;
  __syncthreads();
  if (t == 0) {
    int s = 0;
    for (int i = 0; i < 256; ++i) s += cnt[i];
    *flag = (s > 128) ? 1 : 0;
  }
}

// ---------------------------------------------------------------------------
// Kernel 1: QKV projection via bf16 MFMA, 64x64 tile, BK=32.
// ROUND-12 (= r11 intent): staging double-buffered with register prefetch
// (1 barrier/iter); bf16 branch uses direct uint4 copy (A) + ushort-pair
// shift pack (B^T) — the mechanisms validated in attn's ks/vs32 staging.
// Frag/MFMA/epilogue addressing identical to the round-4/5/9/10 kernel.
// ---------------------------------------------------------------------------
template <typename WT>
__global__ __launch_bounds__(256, 2) void rpr_proj_mfma(
    const void* __restrict__ xq, const void* __restrict__ xk, const void* __restrict__ xv,
    const void* __restrict__ wqp, const void* __restrict__ wkp, const void* __restrict__ wvp,
    const void* __restrict__ bqp, const void* __restrict__ bkp, const void* __restrict__ bvp,
    WT* __restrict__ ws, const int* __restrict__ flagp) {
  const bool f32 = (*flagp != 0);
  const int z = blockIdx.z;
  const void* __restrict__ X = (z == 0) ? xq : (z == 1) ? xk : xv;
  const void* __restrict__ W = (z == 0) ? wqp : (z == 1) ? wkp : wvp;
  const void* __restrict__ Bb = (z == 0) ? bqp : (z == 1) ? bkp : bvp;
  WT* __restrict__ O = ws + (size_t)z * (4096u * 512u);

  __shared__ u32 as32[2][64][20];  // A[m][k] bf16 u32-paired, dbuf
  __shared__ u32 bs32[2][64][20];  // B^T[n][k] bf16 u32-paired, dbuf

  const int t = threadIdx.x;
  const int wvi = t >> 6, lane = t & 63;
  const int quad = lane >> 4, col = lane & 15;
  const int m0 = blockIdx.y * 64, n0 = blockIdx.x * 64;
  const int am = t >> 2, akc = t & 3;          // A map: row, k-chunk of 8
  const int bkx = t & 15, bnx = (t >> 4) * 4;  // B map: k-pair, n-group of 4

  f32x4 acc[4] = {{0.f, 0.f, 0.f, 0.f}, {0.f, 0.f, 0.f, 0.f},
                  {0.f, 0.f, 0.f, 0.f}, {0.f, 0.f, 0.f, 0.f}};

  // tile loaders: global k0-slice -> registers (uniform dtype branch)
  auto loadA = [&](int k0, uint4& ra) {
    if (!f32) {
      ra = *(const uint4*)((const u16*)X + (size_t)(m0 + am) * 512 + k0 + akc * 8);
    } else {
      const float* xf = (const float*)X + (size_t)(m0 + am) * 512 + k0 + akc * 8;
      float4 a = *(const float4*)xf, b = *(const float4*)(xf + 4);
      ra.x = pk2(a.x, a.y); ra.y = pk2(a.z, a.w);
      ra.z = pk2(b.x, b.y); ra.w = pk2(b.z, b.w);
    }
  };
  auto loadB = [&](int k0, uint4& rb) {
    if (!f32) {
      const u16* w0 = (const u16*)W + (size_t)(k0 + 2 * bkx) * 512 + n0 + bnx;
      ushort4 r0 = *(const ushort4*)w0;
      ushort4 r1 = *(const ushort4*)(w0 + 512);
      rb.x = (u32)r0.x | ((u32)r1.x << 16);
      rb.y = (u32)r0.y | ((u32)r1.y << 16);
      rb.z = (u32)r0.z | ((u32)r1.z << 16);
      rb.w = (u32)r0.w | ((u32)r1.w << 16);
    } else {
      float4 r0 = ld4in(W, (size_t)(k0 + 2 * bkx) * 512 + n0 + bnx, true);
      float4 r1 = ld4in(W, (size_t)(k0 + 2 * bkx + 1) * 512 + n0 + bnx, true);
      rb.x = pk2(r0.x, r1.x);
      rb.y = pk2(r0.y, r1.y);
      rb.z = pk2(r0.z, r1.z);
      rb.w = pk2(r0.w, r1.w);
    }
  };

  // preload tile 0 -> buffer 0
  {
    uint4 ra, rb;
    loadA(0, ra);
    loadB(0, rb);
    *(uint4*)&as32[0][am][akc * 4] = ra;
    bs32[0][bnx + 0][bkx] = rb.x;
    bs32[0][bnx + 1][bkx] = rb.y;
    bs32[0][bnx + 2][bkx] = rb.z;
    bs32[0][bnx + 3][bkx] = rb.w;
  }
  __syncthreads();

  for (int it = 0; it < 16; ++it) {
    const int cur = it & 1;
    // prefetch next tile into registers (hidden under MFMA below)
    uint4 ra, rb;
    if (it < 15) {
      loadA((it + 1) * 32, ra);
      loadB((it + 1) * 32, rb);
    }
    // A-frag: A[m=lane&15][k=quad*8+j]
    short8 aF = *(const short8*)((const u16*)&as32[cur][wvi * 16 + col][0] + quad * 8);
#pragma unroll
    for (int c = 0; c < 4; ++c) {
      // B-frag: B[k=quad*8+j][n=lane&15] read from B^T row n
      short8 bF = *(const short8*)((const u16*)&bs32[cur][c * 16 + col][0] + quad * 8);
      acc[c] = __builtin_amdgcn_mfma_f32_16x16x32_bf16(aF, bF, acc[c], 0, 0, 0);
    }
    // write prefetched tile into the alternate buffer
    if (it < 15) {
      *(uint4*)&as32[1 - cur][am][akc * 4] = ra;
      bs32[1 - cur][bnx + 0][bkx] = rb.x;
      bs32[1 - cur][bnx + 1][bkx] = rb.y;
      bs32[1 - cur][bnx + 2][bkx] = rb.z;
      bs32[1 - cur][bnx + 3][bkx] = rb.w;
    }
    __syncthreads();  // alt buffer visible; cur reads done before next overwrite
  }

  const int h = blockIdx.x;  // n0 >> 6
#pragma unroll
  for (int c = 0; c < 4; ++c) {
    float bias = ld1in(Bb, (size_t)(n0 + c * 16 + col), f32);
#pragma unroll
    for (int reg = 0; reg < 4; ++reg) {
      int m = m0 + wvi * 16 + quad * 4 + reg;  // C layout: row = quad*4+reg
      int bb = m >> 10, s = m & 1023;
      O[((size_t)((bb * 8 + h) * 1024 + s)) * 64 + c * 16 + col] =
          f2bf(acc[c][reg] + bias);
    }
  }
}

// ---------------------------------------------------------------------------
// Kernel 2: MFMA flash attention with RPR (round-9/10 validated: K/V dbuf with
// register prefetch, 2 barriers/tile, rid from global, register bins).
// Byte-identical to round 10.
// ---------------------------------------------------------------------------
template <typename WT>
__global__ __launch_bounds__(256, 2) void rpr_attn_mfma(
    const WT* __restrict__ qkv, const int* __restrict__ rpr,
    const void* __restrict__ krpr, void* __restrict__ out,
    const int* __restrict__ flagp) {
  const bool f32 = (*flagp != 0);
  const int bh = blockIdx.y, q0 = blockIdx.x * 64;
  const int b = bh >> 3, h = bh & 7;
  const WT* __restrict__ qh = qkv + (size_t)bh * 65536;
  const WT* __restrict__ kh = qkv + (size_t)(32 + bh) * 65536;
  const WT* __restrict__ vh = qkv + (size_t)(64 + bh) * 65536;

  __shared__ u16 qs[64][72];       // Q rows bf16
  __shared__ u16 ks[2][64][72];    // K-tile [key][d], double-buffered
  __shared__ u32 vs32[2][64][36];  // V^T [d][k-pair] u32-packed, double-buffered
  __shared__ u16 ps[4][16][72];    // per-wave P tile bf16 [q][k]
  __shared__ float krl[11][64];    // krpr fp32
  __shared__ float qrpr[64][12];   // q . krpr[r]

  const int t = threadIdx.x;
  const int wvi = t >> 6, lane = t & 63;
  const int quad = lane >> 4, col = lane & 15;
  const int sr = t >> 2, sc4 = (t & 3) * 16;  // Q/K staging map
  const int kp = t & 31, dg = (t >> 5) * 8;   // V staging map

  // ---- one-time staging (krl, Q, K/V tile 0 -> buffer 0) ----
  for (int i = t; i < 704; i += 256)
    krl[i >> 6][i & 63] = f32 ? ((const float*)krpr)[i] : bf2f(((const u16*)krpr)[i]);
  {
    size_t base = (size_t)(q0 + sr) * 64 + sc4;
    *(uint4*)&qs[sr][sc4] = ld8ws_pk(qh, base);
    *(uint4*)&qs[sr][sc4 + 8] = ld8ws_pk(qh, base + 8);
  }
  {
    size_t kb = (size_t)sr * 64 + sc4;
    *(uint4*)&ks[0][sr][sc4] = ld8ws_pk(kh, kb);
    *(uint4*)&ks[0][sr][sc4 + 8] = ld8ws_pk(kh, kb + 8);
    size_t vb = (size_t)(2 * kp) * 64 + dg;
    uint4 va = ld8ws_pk(vh, vb), vbb = ld8ws_pk(vh, vb + 64);
    vs32[0][dg + 0][kp] = (va.x & 0xffffu) | (vbb.x << 16);
    vs32[0][dg + 1][kp] = (va.x >> 16) | (vbb.x & 0xffff0000u);
    vs32[0][dg + 2][kp] = (va.y & 0xffffu) | (vbb.y << 16);
    vs32[0][dg + 3][kp] = (va.y >> 16) | (vbb.y & 0xffff0000u);
    vs32[0][dg + 4][kp] = (va.z & 0xffffu) | (vbb.z << 16);
    vs32[0][dg + 5][kp] = (va.z >> 16) | (vbb.z & 0xffff0000u);
    vs32[0][dg + 6][kp] = (va.w & 0xffffu) | (vbb.w << 16);
    vs32[0][dg + 7][kp] = (va.w >> 16) | (vbb.w & 0xffff0000u);
  }
  __syncthreads();
  // qrpr[row][r]: thread -> row t>>2, r in {t&3, +4, +8}
  {
    int r = t >> 2, rb = t & 3;
    float d0 = 0.f, d1 = 0.f, d2 = 0.f;
    for (int d = 0; d < 64; ++d) {
      float qv = bf2f(qs[r][d]);
      d0 = fmaf(qv, krl[rb][d], d0);
      d1 = fmaf(qv, krl[rb + 4][d], d1);
      if (rb < 3) d2 = fmaf(qv, krl[rb + 8][d], d2);
    }
    qrpr[r][rb] = d0;
    qrpr[r][rb + 4] = d1;
    if (rb < 3) qrpr[r][rb + 8] = d2;
  }
  // Q A-frags: A[m=lane&15][k=quad*8+j], two k-halves of DH=64
  short8 qA0, qA1;
  {
    const u16* qrow = &qs[wvi * 16 + col][0];
    qA0 = *(const short8*)(qrow + quad * 8);
    qA1 = *(const short8*)(qrow + 32 + quad * 8);
  }
  __syncthreads();  // qrpr visible to all before first tile's softmax

  float l_part[4] = {0.f, 0.f, 0.f, 0.f};
  float bins[4][11] = {};  // registers (LDS atomics are poison — rounds 6/7)
  f32x4 ctx[4] = {{0.f, 0.f, 0.f, 0.f}, {0.f, 0.f, 0.f, 0.f},
                  {0.f, 0.f, 0.f, 0.f}, {0.f, 0.f, 0.f, 0.f}};

  for (int kt = 0; kt < 16; ++kt) {
    const int cur = kt & 1;
    // (A) prefetch next K/V tile into registers (latency hidden under B-E)
    uint4 pk0, pk1, pva, pvb;
    if (kt < 15) {
      size_t kb = (size_t)((kt + 1) * 64 + sr) * 64 + sc4;
      pk0 = ld8ws_pk(kh, kb);
      pk1 = ld8ws_pk(kh, kb + 8);
      size_t vb = (size_t)((kt + 1) * 64 + 2 * kp) * 64 + dg;
      pva = ld8ws_pk(vh, vb);
      pvb = ld8ws_pk(vh, vb + 64);
    }
    // rid direct from global (L2-hot; validated round 9)
    int rid[4][4];
    {
      const int* rbase =
          rpr + (size_t)(q0 + wvi * 16 + quad * 4) * 1024 + kt * 64 + col;
#pragma unroll
      for (int reg = 0; reg < 4; ++reg)
#pragma unroll
        for (int c = 0; c < 4; ++c) rid[c][reg] = rbase[reg * 1024 + c * 16];
    }
    // (B) scores: QK^T via MFMA, 4 chunks of 16 keys
    f32x4 sc[4];
#pragma unroll
    for (int c = 0; c < 4; ++c) {
      const u16* kb = &ks[cur][c * 16 + col][0];
      short8 kB0 = *(const short8*)(kb + quad * 8);
      short8 kB1 = *(const short8*)(kb + 32 + quad * 8);
      f32x4 a = {0.f, 0.f, 0.f, 0.f};
      a = __builtin_amdgcn_mfma_f32_16x16x32_bf16(qA0, kB0, a, 0, 0, 0);
      a = __builtin_amdgcn_mfma_f32_16x16x32_bf16(qA1, kB1, a, 0, 0, 0);
      sc[c] = a;
    }
    // (C) p = exp((s + rpr-bias)/8); accumulate l, register bins; write P bf16
#pragma unroll
    for (int c = 0; c < 4; ++c) {
#pragma unroll
      for (int reg = 0; reg < 4; ++reg) {
        int row = wvi * 16 + quad * 4 + reg;  // C layout: row = quad*4+reg
        float p = __expf((sc[c][reg] + qrpr[row][rid[c][reg]]) * 0.125f);
        l_part[reg] += p;
#pragma unroll
        for (int r = 0; r < 11; ++r) bins[reg][r] += (rid[c][reg] == r) ? p : 0.f;
        ps[wvi][quad * 4 + reg][c * 16 + col] = f2bf(p);
      }
    }
    __syncthreads();  // P visible for A-frag reads (validated round 5)

    // (D) PV: P (A-layout) x V^T rows (B-layout)
    short8 pA0, pA1;
    {
      const u16* prow = &ps[wvi][col][0];
      pA0 = *(const short8*)(prow + quad * 8);
      pA1 = *(const short8*)(prow + 32 + quad * 8);
    }
#pragma unroll
    for (int c = 0; c < 4; ++c) {
      const u16* vrow = (const u16*)&vs32[cur][c * 16 + col][0];
      short8 vB0 = *(const short8*)(vrow + quad * 8);
      short8 vB1 = *(const short8*)(vrow + 32 + quad * 8);
      ctx[c] = __builtin_amdgcn_mfma_f32_16x16x32_bf16(pA0, vB0, ctx[c], 0, 0, 0);
      ctx[c] = __builtin_amdgcn_mfma_f32_16x16x32_bf16(pA1, vB1, ctx[c], 0, 0, 0);
    }
    // (E) write prefetched tile into the alternate buffer
    if (kt < 15) {
      *(uint4*)&ks[1 - cur][sr][sc4] = pk0;
      *(uint4*)&ks[1 - cur][sr][sc4 + 8] = pk1;
      vs32[1 - cur][dg + 0][kp] = (pva.x & 0xffffu) | (pvb.x << 16);
      vs32[1 - cur][dg + 1][kp] = (pva.x >> 16) | (pvb.x & 0xffff0000u);
      vs32[1 - cur][dg + 2][kp] = (pva.y & 0xffffu) | (pvb.y << 16);
      vs32[1 - cur][dg + 3][kp] = (pva.y >> 16) | (pvb.y & 0xffff0000u);
      vs32[1 - cur][dg + 4][kp] = (pva.z & 0xffffu) | (pvb.z << 16);
      vs32[1 - cur][dg + 5][kp] = (pva.z >> 16) | (pvb.z & 0xffff0000u);
      vs32[1 - cur][dg + 6][kp] = (pva.w & 0xffffu) | (pvb.w << 16);
      vs32[1 - cur][dg + 7][kp] = (pva.w >> 16) | (pvb.w & 0xffff0000u);
    }
    __syncthreads();  // next tile's frag reads see the new buffer
  }

  // ---- epilogue: reduce l/bins over 16 lanes of each quad ----
#pragma unroll
  for (int off = 1; off < 16; off <<= 1) {
#pragma unroll
    for (int reg = 0; reg < 4; ++reg) {
      l_part[reg] += __shfl_xor(l_part[reg], off);
#pragma unroll
      for (int r = 0; r < 11; ++r) bins[reg][r] += __shfl_xor(bins[reg][r], off);
    }
  }
  // value-side RPR + normalize + store
#pragma unroll
  for (int reg = 0; reg < 4; ++reg) {
    int row = wvi * 16 + quad * 4 + reg;
    float inv = 1.f / l_part[reg];
#pragma unroll
    for (int c = 0; c < 4; ++c) {
      float v = ctx[c][reg];
#pragma unroll
      for (int r = 0; r < 11; ++r) v = fmaf(bins[reg][r], krl[r][c * 16 + col], v);
      size_t oidx = (size_t)(b * 1024 + q0 + row) * 512 + h * 64 + c * 16 + col;
      if (f32) ((float*)out)[oidx] = v * inv;
      else ((u16*)out)[oidx] = f2bf(v * inv);
    }
  }
}

// ---------------------------------------------------------------------------
extern "C" void kernel_launch(void* const* d_in, const int* in_sizes, int n_in,
                              void* d_out, int out_size, void* d_ws, size_t ws_size,
                              hipStream_t stream) {
  const void* q = d_in[0];
  const void* k = d_in[1];
  const void* v = d_in[2];
  const int* rpr = (const int*)d_in[3];
  const void* wq = d_in[4];
  const void* bq = d_in[5];
  const void* wk = d_in[6];
  const void* bk = d_in[7];
  const void* wv = d_in[8];
  const void* bv = d_in[9];
  const void* krpr = d_in[10];

  int* flag = (int*)d_ws;
  u16* ws = (u16*)((char*)d_ws + 1024);  // bf16 ws: 12.6 MB (validated r10)

  rpr_detect_kernel<<<1, 256, 0, stream>>>((const u16*)q, flag);
  rpr_proj_mfma<u16><<<dim3(8, 64, 3), 256, 0, stream>>>(
      q, k, v, wq, wk, wv, bq, bk, bv, ws, flag);
  rpr_attn_mfma<u16><<<dim3(16, 32), 256, 0, stream>>>(
      ws, rpr, krpr, d_out, flag);
}